// Round 1
// baseline (1436.723 us; speedup 1.0000x reference)
//
#include <hip/hip_runtime.h>

// PiNet2 fused implementation, fp32 VALU version.
// Sizes (fixed by the problem): N_ATOMS=20000, N_PAIRS=640000, C=64, NB=4.

#define WAVES_PER_BLOCK 4
#define PAIRS_PER_WAVE 8   // 8 items (pairs/atoms/rows) per wave, lane = channel

__device__ __forceinline__ float fast_tanh(float x) {
    // tanh(x) = 1 - 2/(e^{2x}+1); robust at +-inf, accurate ~1e-6 rel.
    float t = __expf(2.0f * x);
    return 1.0f - __fdividef(2.0f, t + 1.0f);
}

__device__ __forceinline__ void store8(float* dst, const float v[8]) {
    *(float4*)(dst)     = make_float4(v[0], v[1], v[2], v[3]);
    *(float4*)(dst + 4) = make_float4(v[4], v[5], v[6], v[7]);
}

__device__ __forceinline__ void fma8(const float* row, float wv, float acc[8]) {
    float4 x0 = *(const float4*)(row);
    float4 x1 = *(const float4*)(row + 4);
    acc[0] = fmaf(x0.x, wv, acc[0]);
    acc[1] = fmaf(x0.y, wv, acc[1]);
    acc[2] = fmaf(x0.z, wv, acc[2]);
    acc[3] = fmaf(x0.w, wv, acc[3]);
    acc[4] = fmaf(x1.x, wv, acc[4]);
    acc[5] = fmaf(x1.y, wv, acc[5]);
    acc[6] = fmaf(x1.z, wv, acc[6]);
    acc[7] = fmaf(x1.w, wv, acc[7]);
}

// ---------------- K0: W3 = Wpp3a @ Wpp3b (64x64) ----------------
__global__ __launch_bounds__(256) void k_w3(const float* __restrict__ A,
                                            const float* __restrict__ B,
                                            float* __restrict__ W3) {
    int t = threadIdx.x;
#pragma unroll
    for (int e = 0; e < 16; ++e) {
        int idx = t * 16 + e;
        int k = idx >> 6, c = idx & 63;
        float s = 0.f;
        for (int m = 0; m < 64; ++m) s = fmaf(A[k * 64 + m], B[m * 64 + c], s);
        W3[idx] = s;
    }
}

// ---------------- K1: p1h = tanh(tanh(p1@Wa+ba)@Wb+bb) ----------------
__global__ __launch_bounds__(256) void k_p1h(const float* __restrict__ p1,
                                             const float* __restrict__ Wa,
                                             const float* __restrict__ ba,
                                             const float* __restrict__ Wb,
                                             const float* __restrict__ bb,
                                             float* __restrict__ p1h) {
    __shared__ float act[WAVES_PER_BLOCK][64][8];
    const int w = threadIdx.x >> 6, lane = threadIdx.x & 63;
    const int a0 = blockIdx.x * 32 + w * 8;
    {
        float t[8];
#pragma unroll
        for (int p = 0; p < 8; ++p) t[p] = p1[(a0 + p) * 64 + lane];
        store8(&act[w][lane][0], t);
    }
    __syncthreads();
    float acc[8];
    {
        float bv = ba[lane];
#pragma unroll
        for (int p = 0; p < 8; ++p) acc[p] = bv;
        for (int k = 0; k < 64; ++k) fma8(&act[w][k][0], Wa[k * 64 + lane], acc);
    }
    __syncthreads();
    {
        float t[8];
#pragma unroll
        for (int p = 0; p < 8; ++p) t[p] = fast_tanh(acc[p]);
        store8(&act[w][lane][0], t);
    }
    __syncthreads();
    {
        float bv = bb[lane];
#pragma unroll
        for (int p = 0; p < 8; ++p) acc[p] = bv;
        for (int k = 0; k < 64; ++k) fma8(&act[w][k][0], Wb[k * 64 + lane], acc);
    }
#pragma unroll
    for (int p = 0; p < 8; ++p) p1h[(a0 + p) * 64 + lane] = fast_tanh(acc[p]);
}

// ---------------- K2: Y[r] = X[r] @ W (rows of 64) ----------------
__global__ __launch_bounds__(256) void k_rowmm(const float* __restrict__ X,
                                               const float* __restrict__ W,
                                               float* __restrict__ Y) {
    __shared__ float act[WAVES_PER_BLOCK][64][8];
    const int w = threadIdx.x >> 6, lane = threadIdx.x & 63;
    const int r0 = blockIdx.x * 32 + w * 8;
    {
        float t[8];
#pragma unroll
        for (int p = 0; p < 8; ++p) t[p] = X[(r0 + p) * 64 + lane];
        store8(&act[w][lane][0], t);
    }
    __syncthreads();
    float acc[8];
#pragma unroll
    for (int p = 0; p < 8; ++p) acc[p] = 0.f;
    for (int k = 0; k < 64; ++k) fma8(&act[w][k][0], W[k * 64 + lane], acc);
#pragma unroll
    for (int p = 0; p < 8; ++p) Y[(r0 + p) * 64 + lane] = acc[p];
}

// ---------------- K3: fused per-pair chain ----------------
__global__ __launch_bounds__(256) void k_pairs(
    const int* __restrict__ ind,
    const float* __restrict__ p1h, const float* __restrict__ p3h,
    const float* __restrict__ diff, const float* __restrict__ basis,
    const float* __restrict__ Wpi1, const float* __restrict__ bpi1,
    const float* __restrict__ Wpi2, const float* __restrict__ bpi2,
    const float* __restrict__ Wii1, const float* __restrict__ Wii2,
    const float* __restrict__ Wpxi, const float* __restrict__ Wpxj,
    float* __restrict__ outp1, float* __restrict__ outp3) {
    __shared__ float act[WAVES_PER_BLOCK][384][8];  // 48 KB
    const int w = threadIdx.x >> 6, lane = threadIdx.x & 63;
    const int pbase = blockIdx.x * 32 + w * 8;

    int ii[8], jj[8];
#pragma unroll
    for (int p = 0; p < 8; ++p) {
        ii[p] = ind[(pbase + p) * 2 + 0];
        jj[p] = ind[(pbase + p) * 2 + 1];
    }
    // stage [p1h_i ; p1h_j] -> act rows 0..127
    {
        float ti[8], tj[8];
#pragma unroll
        for (int p = 0; p < 8; ++p) {
            ti[p] = p1h[ii[p] * 64 + lane];
            tj[p] = p1h[jj[p] * 64 + lane];
        }
        store8(&act[w][lane][0], ti);
        store8(&act[w][64 + lane][0], tj);
    }
    __syncthreads();
    float acc[8];
    // ---- pi1: K=128 -> 64, +bias, tanh ----
    {
        float bv = bpi1[lane];
#pragma unroll
        for (int p = 0; p < 8; ++p) acc[p] = bv;
        for (int k = 0; k < 128; ++k) fma8(&act[w][k][0], Wpi1[k * 64 + lane], acc);
    }
    __syncthreads();
    {
        float t[8];
#pragma unroll
        for (int p = 0; p < 8; ++p) t[p] = fast_tanh(acc[p]);
        store8(&act[w][lane][0], t);
    }
    __syncthreads();
    // ---- pi2: K=64 -> 256 (lane holds out 4c..4c+3), +bias, tanh, basis contract ----
    float i1v[8];
    {
        float4 bv = *(const float4*)&bpi2[lane * 4];
        float a0[8], a1[8], a2[8], a3[8];
#pragma unroll
        for (int p = 0; p < 8; ++p) { a0[p] = bv.x; a1[p] = bv.y; a2[p] = bv.z; a3[p] = bv.w; }
        for (int k = 0; k < 64; ++k) {
            float4 wv = *(const float4*)&Wpi2[k * 256 + lane * 4];
            fma8(&act[w][k][0], wv.x, a0);
            fma8(&act[w][k][0], wv.y, a1);
            fma8(&act[w][k][0], wv.z, a2);
            fma8(&act[w][k][0], wv.w, a3);
        }
#pragma unroll
        for (int p = 0; p < 8; ++p) {
            float4 bs = *(const float4*)&basis[(pbase + p) * 4];
            i1v[p] = fast_tanh(a0[p]) * bs.x + fast_tanh(a1[p]) * bs.y +
                     fast_tanh(a2[p]) * bs.z + fast_tanh(a3[p]) * bs.w;
        }
    }
    __syncthreads();
    store8(&act[w][lane][0], i1v);
    __syncthreads();
    // ---- ii1: K=64 -> 64, tanh (no bias) ----
    {
#pragma unroll
        for (int p = 0; p < 8; ++p) acc[p] = 0.f;
        for (int k = 0; k < 64; ++k) fma8(&act[w][k][0], Wii1[k * 64 + lane], acc);
    }
    __syncthreads();
    {
        float t[8];
#pragma unroll
        for (int p = 0; p < 8; ++p) t[p] = fast_tanh(acc[p]);
        store8(&act[w][lane][0], t);
    }
    __syncthreads();
    // ---- ii2: K=64 -> 192, tanh; atomic p1_new += i1_2 ----
    float i1_1[8], i1_3[8];
    {
        float b0[8], b1[8], b2[8];
#pragma unroll
        for (int p = 0; p < 8; ++p) { b0[p] = 0.f; b1[p] = 0.f; b2[p] = 0.f; }
        for (int k = 0; k < 64; ++k) {
            float w0 = Wii2[k * 192 + lane];
            float w1 = Wii2[k * 192 + 64 + lane];
            float w2 = Wii2[k * 192 + 128 + lane];
            fma8(&act[w][k][0], w0, b0);
            fma8(&act[w][k][0], w1, b1);
            fma8(&act[w][k][0], w2, b2);
        }
#pragma unroll
        for (int p = 0; p < 8; ++p) {
            i1_1[p] = fast_tanh(b0[p]);
            float i12 = fast_tanh(b1[p]);
            i1_3[p] = fast_tanh(b2[p]);
            atomicAdd(&outp1[ii[p] * 64 + lane], i12);
        }
    }
    __syncthreads();
    // ---- stage p3h rows: act row x*128 + side*64 + c ----
    for (int x = 0; x < 3; ++x) {
        float ti[8], tj[8];
#pragma unroll
        for (int p = 0; p < 8; ++p) {
            ti[p] = p3h[(ii[p] * 3 + x) * 64 + lane];
            tj[p] = p3h[(jj[p] * 3 + x) * 64 + lane];
        }
        store8(&act[w][x * 128 + lane][0], ti);
        store8(&act[w][x * 128 + 64 + lane][0], tj);
    }
    __syncthreads();
    // ---- i3 = p3h_i@Wpxi + p3h_j@Wpxj, scale, atomic p3_new ----
    {
        float c0[8], c1[8], c2[8];
#pragma unroll
        for (int p = 0; p < 8; ++p) { c0[p] = 0.f; c1[p] = 0.f; c2[p] = 0.f; }
        for (int k = 0; k < 64; ++k) {
            float wv = Wpxi[k * 64 + lane];
            fma8(&act[w][0 * 128 + k][0], wv, c0);
            fma8(&act[w][1 * 128 + k][0], wv, c1);
            fma8(&act[w][2 * 128 + k][0], wv, c2);
        }
        for (int k = 0; k < 64; ++k) {
            float wv = Wpxj[k * 64 + lane];
            fma8(&act[w][0 * 128 + 64 + k][0], wv, c0);
            fma8(&act[w][1 * 128 + 64 + k][0], wv, c1);
            fma8(&act[w][2 * 128 + 64 + k][0], wv, c2);
        }
#pragma unroll
        for (int p = 0; p < 8; ++p) {
            const float* dptr = &diff[(pbase + p) * 3];
            float d0 = dptr[0], d1 = dptr[1], d2 = dptr[2];
            int base = ii[p] * 3 * 64 + lane;
            atomicAdd(&outp3[base + 0 * 64], fmaf(c0[p], i1_3[p], d0 * i1_1[p]));
            atomicAdd(&outp3[base + 1 * 64], fmaf(c1[p], i1_3[p], d1 * i1_1[p]));
            atomicAdd(&outp3[base + 2 * 64], fmaf(c2[p], i1_3[p], d2 * i1_1[p]));
        }
    }
}

// ---------------- K4: per-atom epilogue (in place over d_out) ----------------
__global__ __launch_bounds__(256) void k_final(const float* __restrict__ Wdi,
                                               const float* __restrict__ Wdj,
                                               float* __restrict__ outp1,
                                               float* __restrict__ outp3) {
    __shared__ float act[WAVES_PER_BLOCK][192][8];
    const int w = threadIdx.x >> 6, lane = threadIdx.x & 63;
    const int a0 = blockIdx.x * 32 + w * 8;
    for (int x = 0; x < 3; ++x) {
        float t[8];
#pragma unroll
        for (int p = 0; p < 8; ++p) t[p] = outp3[((a0 + p) * 3 + x) * 64 + lane];
        store8(&act[w][x * 64 + lane][0], t);
    }
    __syncthreads();
    float u0[8], u1[8], u2[8], v0[8], v1[8], v2[8];
#pragma unroll
    for (int p = 0; p < 8; ++p) {
        u0[p] = u1[p] = u2[p] = 0.f;
        v0[p] = v1[p] = v2[p] = 0.f;
    }
    for (int k = 0; k < 64; ++k) {
        float wi = Wdi[k * 64 + lane];
        float wj = Wdj[k * 64 + lane];
        fma8(&act[w][k][0], wi, u0);
        fma8(&act[w][64 + k][0], wi, u1);
        fma8(&act[w][128 + k][0], wi, u2);
        fma8(&act[w][k][0], wj, v0);
        fma8(&act[w][64 + k][0], wj, v1);
        fma8(&act[w][128 + k][0], wj, v2);
    }
#pragma unroll
    for (int p = 0; p < 8; ++p) {
        float dot = u0[p] * v0[p] + u1[p] * v1[p] + u2[p] * v2[p];
        int o1 = (a0 + p) * 64 + lane;
        float p1t = dot + outp1[o1];
        outp1[o1] = p1t;
#pragma unroll
        for (int x = 0; x < 3; ++x) {
            int o3 = ((a0 + p) * 3 + x) * 64 + lane;
            outp3[o3] = act[w][x * 64 + lane][p] * p1t;
        }
    }
}

extern "C" void kernel_launch(void* const* d_in, const int* in_sizes, int n_in,
                              void* d_out, int out_size, void* d_ws, size_t ws_size,
                              hipStream_t stream) {
    const int*   ind   = (const int*)d_in[0];
    const float* p1    = (const float*)d_in[1];
    const float* p3    = (const float*)d_in[2];
    const float* diff  = (const float*)d_in[3];
    const float* basis = (const float*)d_in[4];
    const float* Wpp1a = (const float*)d_in[5];
    const float* bpp1a = (const float*)d_in[6];
    const float* Wpp1b = (const float*)d_in[7];
    const float* bpp1b = (const float*)d_in[8];
    const float* Wpi1  = (const float*)d_in[9];
    const float* bpi1  = (const float*)d_in[10];
    const float* Wpi2  = (const float*)d_in[11];
    const float* bpi2  = (const float*)d_in[12];
    const float* Wii1  = (const float*)d_in[13];
    const float* Wii2  = (const float*)d_in[14];
    const float* Wpp3a = (const float*)d_in[15];
    const float* Wpp3b = (const float*)d_in[16];
    const float* Wpxi  = (const float*)d_in[17];
    const float* Wpxj  = (const float*)d_in[18];
    const float* Wdi   = (const float*)d_in[19];
    const float* Wdj   = (const float*)d_in[20];

    const int n_atoms = in_sizes[1] / 64;   // 20000
    const int n_pairs = in_sizes[0] / 2;    // 640000

    float* outp1 = (float*)d_out;
    float* outp3 = outp1 + (size_t)n_atoms * 64;

    float* W3  = (float*)d_ws;              // 4096 floats
    float* p1h = W3 + 4096;                 // n_atoms*64
    float* p3h = p1h + (size_t)n_atoms * 64;  // n_atoms*192

    // zero accumulators (d_out holds p1_new / p3_new during K3)
    hipMemsetAsync(d_out, 0, (size_t)out_size * sizeof(float), stream);

    k_w3<<<1, 256, 0, stream>>>(Wpp3a, Wpp3b, W3);
    k_p1h<<<n_atoms / 32, 256, 0, stream>>>(p1, Wpp1a, bpp1a, Wpp1b, bpp1b, p1h);
    k_rowmm<<<(n_atoms * 3) / 32, 256, 0, stream>>>(p3, W3, p3h);
    k_pairs<<<n_pairs / 32, 256, 0, stream>>>(ind, p1h, p3h, diff, basis,
                                              Wpi1, bpi1, Wpi2, bpi2,
                                              Wii1, Wii2, Wpxi, Wpxj,
                                              outp1, outp3);
    k_final<<<n_atoms / 32, 256, 0, stream>>>(Wdi, Wdj, outp1, outp3);
}